// Round 7
// baseline (636.908 us; speedup 1.0000x reference)
//
#include <hip/hip_runtime.h>
#include <hip/hip_bf16.h>

// ---------------------------------------------------------------------------
// Attention_15573551415521: b=8, c=512, n=4096
//   qk  = W_qk x          -> qkT [b][n][1024] bf16
//   W_ov = W_o W_v        (512x512 folded)
//   U   = W_ov x          -> [b][512][n] bf16
//   P   = exp(scale q^T k); y = (U P^T)/rowsum -> fp32 d_out
// All GEMMs: 256x256 tile, BK=64, 2 K-tiles/iter, 8 waves (2Mx4N), 8-phase
// schedule w/ counted vmcnt (T3+T4), XOR-swizzled LDS (T2, HW-proven 0-conflict
// in r5/r6), setprio around MFMA clusters (T5). 128 KiB LDS, dbuf by K-tile
// parity. Region free/deadline analysis gives vmcnt(2) at phases 3 & 7.
// ---------------------------------------------------------------------------

typedef __bf16 bf16x8 __attribute__((ext_vector_type(8)));
typedef float f32x4 __attribute__((ext_vector_type(4)));
typedef __hip_bfloat16 bf16_t;

static __device__ __forceinline__ void glds16(const void* g, void* l) {
  __builtin_amdgcn_global_load_lds(
      (__attribute__((address_space(1))) const void*)g,
      (__attribute__((address_space(3))) void*)l, 16, 0, 0);
}

#define BAR asm volatile("s_barrier" ::: "memory")
#define LGKM0 asm volatile("s_waitcnt lgkmcnt(0)" ::: "memory")
#define LGKM8 asm volatile("s_waitcnt lgkmcnt(8)" ::: "memory")
#define VM0 asm volatile("s_waitcnt vmcnt(0)" ::: "memory")
#define VM2 asm volatile("s_waitcnt vmcnt(2)" ::: "memory")

// read A-frags fm = qm*4..qm*4+3 (both kk) from buf
#define READ_A(buf, qm)                                                       \
  {                                                                           \
    const int rgA = (((buf)*2 + wm) << 14);                                   \
    _Pragma("unroll") for (int j = 0; j < 4; ++j) {                           \
      const int ro = rgA + ((((qm)*4 + j)*16 + lr) << 7);                     \
      _Pragma("unroll") for (int kk = 0; kk < 2; ++kk)                        \
        av[j][kk] = *(const bf16x8*)(lds + ro + ((kk*64 + lk*16) ^ swz));     \
    }                                                                         \
  }
// read B-frags fn = qn*2..qn*2+1 (both kk) from buf
#define READ_B(buf, qn)                                                       \
  {                                                                           \
    const int rgB = 65536 + (((buf)*2 + bh) << 14) + bsub;                    \
    _Pragma("unroll") for (int n = 0; n < 2; ++n) {                           \
      const int ro = rgB + ((((qn)*2 + n)*16 + lr) << 7);                     \
      _Pragma("unroll") for (int kk = 0; kk < 2; ++kk)                        \
        bv[n][kk] = *(const bf16x8*)(lds + ro + ((kk*64 + lk*16) ^ swz));     \
    }                                                                         \
  }
// 16 MFMA: quadrant (qm, qn), setprio wrapped (T5)
#define MFMA_Q(qm, qn)                                                        \
  __builtin_amdgcn_s_setprio(1);                                              \
  _Pragma("unroll") for (int j = 0; j < 4; ++j)                               \
    _Pragma("unroll") for (int n = 0; n < 2; ++n)                             \
      _Pragma("unroll") for (int kk = 0; kk < 2; ++kk)                        \
        acc[(qm)*4 + j][(qn)*2 + n] =                                         \
            __builtin_amdgcn_mfma_f32_16x16x32_bf16(                          \
                av[j][kk], bv[n][kk], acc[(qm)*4 + j][(qn)*2 + n], 0, 0, 0);  \
  __builtin_amdgcn_s_setprio(0);

// MODE 0: bf16 store | MODE 2: P=exp(acc*scale) + rowsum atomic (row=M)
// MODE 5: fp32 store of acc/rowsum[col] (col=N)
template <int MODE>
__global__ void __launch_bounds__(512, 2)
gemm8(const bf16_t* __restrict__ A, long long strideA, int lda,
      const bf16_t* __restrict__ Bt, long long strideB, int ldb,
      void* __restrict__ Cv, long long strideC, int ldc,
      int K, float scale, float* __restrict__ rowsum, int strideRS) {
  __shared__ char lds[131072];  // A: 4 regions x 16KB @0; B: 4 regions @65536
  const int tid = threadIdx.x;
  const int lane = tid & 63;
  const int wid = tid >> 6;                 // 8 waves
  const int wm = wid >> 2, wn = wid & 3;    // 2 x 4; per-wave out 128x64
  const int lr = lane & 15, lk = lane >> 4;
  const int swz = (lr & 7) << 4;
  const int bh = wn >> 1, bsub = (wn & 1) << 13;
  const int b = blockIdx.z;

  const char* Ab = (const char*)(A + (long long)b*strideA + (size_t)blockIdx.x*256*lda);
  const char* Bb = (const char*)(Bt + (long long)b*strideB + (size_t)blockIdx.y*256*ldb);
  const size_t ldab = (size_t)lda*2, ldbb = (size_t)ldb*2;

  // stage one 128-row half-tile (16KB): linear LDS dest, inverse-swizzled src
  auto stage = [&](int m, int buf, int half, int kt) {
    const char* src = m ? Bb : Ab;
    const size_t ld = m ? ldbb : ldab;
    char* dst = lds + (m << 16) + ((buf*2 + half) << 14);
#pragma unroll
    for (int c = 0; c < 2; ++c) {
      const int oin = wid*2048 + c*1024 + lane*16;
      const int row = half*128 + (oin >> 7);
      const int kb = (oin & 127) ^ (((oin >> 7) & 7) << 4);
      glds16(src + (size_t)row*ld + (size_t)kt*128 + kb, dst + wid*2048 + c*1024);
    }
  };

  f32x4 acc[8][4] = {};
  bf16x8 av[4][2], bv[2][2];
  const int niter = K >> 7;  // 2 K-tiles (BK=64) per iteration

  // prologue: K-tile0 complete + A(1)h0; first 4 half-tiles must land
  stage(0,0,0,0); stage(0,0,1,0); stage(1,0,0,0); stage(1,0,1,0);
  stage(0,1,0,1);
  VM2; BAR;

  for (int i = 0; i < niter; ++i) {
    const bool nl = (i + 1 < niter);
    const int o1 = 2*i + 1, e2 = 2*i + 2, o3 = 2*i + 3;
    // P0: Ktile e quad(0,0); stage A(o1)h1 (A[1] free since prev P7)
    READ_A(0,0); READ_B(0,0); stage(0,1,1,o1);
    LGKM8; BAR; LGKM0; MFMA_Q(0,0); BAR;
    // P1: quad(0,1); stage B(o1)h0
    READ_B(0,1); stage(1,1,0,o1);
    BAR; LGKM0; MFMA_Q(0,1); BAR;
    // P2: quad(1,1); stage B(o1)h1
    READ_A(0,1); stage(1,1,1,o1);
    BAR; LGKM0; MFMA_Q(1,1); BAR;
    // P3: quad(1,0) (B fn0-1 re-read); stage A(e2)h0; vmcnt gate for Ktile o
    READ_B(0,0); if (nl) stage(0,0,0,e2);
    BAR; LGKM0; MFMA_Q(1,0);
    if (nl) { VM2; } else { VM0; }
    BAR;
    // P4: Ktile o quad(0,0); stage A(e2)h1
    READ_A(1,0); READ_B(1,0); if (nl) stage(0,0,1,e2);
    LGKM8; BAR; LGKM0; MFMA_Q(0,0); BAR;
    // P5: quad(0,1); stage B(e2)h0
    READ_B(1,1); if (nl) stage(1,0,0,e2);
    BAR; LGKM0; MFMA_Q(0,1); BAR;
    // P6: quad(1,1); stage B(e2)h1
    READ_A(1,1); if (nl) stage(1,0,1,e2);
    BAR; LGKM0; MFMA_Q(1,1); BAR;
    // P7: quad(1,0); stage A(o3)h0; vmcnt gate for Ktile e2
    READ_B(1,0); if (nl) stage(0,1,0,o3);
    BAR; LGKM0; MFMA_Q(1,0);
    if (nl) { VM2; }
    BAR;
  }

  // epilogue: C/D layout col=lane&15, row=(lane>>4)*4+reg (m89-verified)
  const int mbase = blockIdx.x*256 + wm*128;
  const int nbase = blockIdx.y*256 + wn*64;

  if (MODE == 0) {
    bf16_t* C = (bf16_t*)Cv + (long long)b * strideC;
#pragma unroll
    for (int fm = 0; fm < 8; ++fm)
#pragma unroll
      for (int fn = 0; fn < 4; ++fn)
#pragma unroll
        for (int r = 0; r < 4; ++r) {
          const int row = mbase + fm*16 + lk*4 + r;
          const int col = nbase + fn*16 + lr;
          C[(size_t)row*ldc + col] = __float2bfloat16(acc[fm][fn][r]);
        }
  } else if (MODE == 2) {
    bf16_t* P = (bf16_t*)Cv + (long long)b * strideC;
    float* rs = rowsum + (long long)b * strideRS;
#pragma unroll
    for (int fm = 0; fm < 8; ++fm)
#pragma unroll
      for (int r = 0; r < 4; ++r) {
        const int row = mbase + fm*16 + lk*4 + r;
        float s = 0.f;
#pragma unroll
        for (int fn = 0; fn < 4; ++fn) {
          const float v = __expf(acc[fm][fn][r] * scale);
          const int col = nbase + fn*16 + lr;
          P[(size_t)row*ldc + col] = __float2bfloat16(v);
          s += v;
        }
        s += __shfl_xor(s, 1);
        s += __shfl_xor(s, 2);
        s += __shfl_xor(s, 4);
        s += __shfl_xor(s, 8);
        if (lr == 0) atomicAdd(&rs[row], s);
      }
  } else {  // MODE 5
    float* O = (float*)Cv + (long long)b * strideC;
    const float* rs = rowsum + (long long)b * strideRS;
#pragma unroll
    for (int fn = 0; fn < 4; ++fn) {
      const int col = nbase + fn*16 + lr;
      const float inv = 1.0f / rs[col];
#pragma unroll
      for (int fm = 0; fm < 8; ++fm)
#pragma unroll
        for (int r = 0; r < 4; ++r) {
          const int row = mbase + fm*16 + lk*4 + r;
          O[(size_t)row*ldc + col] = acc[fm][fn][r] * inv;
        }
    }
  }
}

__global__ void cast_f32_bf16(const float* __restrict__ in, bf16_t* __restrict__ out, int n) {
  const int i = blockIdx.x * blockDim.x + threadIdx.x;
  if (i < n) out[i] = __float2bfloat16(in[i]);
}

__global__ void zero_f32(float* __restrict__ p, int n) {
  const int i = blockIdx.x * blockDim.x + threadIdx.x;
  if (i < n) p[i] = 0.f;
}

// x [8][512][4096] f32 -> xT [8][4096][512] bf16
__global__ void transpose_cast(const float* __restrict__ x, bf16_t* __restrict__ xT) {
  __shared__ float t[32][33];
  const int b = blockIdx.z;
  const int n0 = blockIdx.x * 32, c0 = blockIdx.y * 32;
  const int tx = threadIdx.x & 31, ty = threadIdx.x >> 5;  // 32x8
  const float* xb = x + (size_t)b * (512 * 4096);
#pragma unroll
  for (int i = 0; i < 32; i += 8)
    t[ty + i][tx] = xb[(size_t)(c0 + ty + i) * 4096 + n0 + tx];
  __syncthreads();
  bf16_t* xo = xT + (size_t)b * (4096 * 512);
#pragma unroll
  for (int i = 0; i < 32; i += 8)
    xo[(size_t)(n0 + ty + i) * 512 + c0 + tx] = __float2bfloat16(t[tx][ty + i]);
}

// 512x512 f32 -> transposed bf16 (for W_v^T)
__global__ void transpose_cast_512(const float* __restrict__ in, bf16_t* __restrict__ out) {
  __shared__ float t[32][33];
  const int r0 = blockIdx.x * 32, c0 = blockIdx.y * 32;
  const int tx = threadIdx.x & 31, ty = threadIdx.x >> 5;
#pragma unroll
  for (int i = 0; i < 32; i += 8)
    t[ty + i][tx] = in[(size_t)(r0 + ty + i) * 512 + c0 + tx];
  __syncthreads();
#pragma unroll
  for (int i = 0; i < 32; i += 8)
    out[(size_t)(c0 + ty + i) * 512 + r0 + tx] = __float2bfloat16(t[tx][ty + i]);
}

extern "C" void kernel_launch(void* const* d_in, const int* in_sizes, int n_in,
                              void* d_out, int out_size, void* d_ws, size_t ws_size,
                              hipStream_t stream) {
  const float* x = (const float*)d_in[0];
  const float* wqkv = (const float*)d_in[1];
  const float* wout = (const float*)d_in[2];
  char* ws = (char*)d_ws;

  // workspace layout (bytes)
  const size_t o_qkT = 0;             // 8*4096*1024*2 = 67108864
  const size_t o_U   = 67108864ull;   // 8*512*4096*2  = 33554432
  const size_t o_wqk = 100663296ull;  // 1048576
  const size_t o_wo  = 101711872ull;  // 524288
  const size_t o_wvT = 102236160ull;  // 524288
  const size_t o_wov = 102760448ull;  // 524288
  const size_t o_rs  = 103284736ull;  // 131072
  const size_t o_xT  = 103415808ull;  // 33554432; P overlays xT afterwards

  bf16_t* qkT  = (bf16_t*)(ws + o_qkT);
  bf16_t* U    = (bf16_t*)(ws + o_U);
  bf16_t* wqkb = (bf16_t*)(ws + o_wqk);
  bf16_t* wob  = (bf16_t*)(ws + o_wo);
  bf16_t* wvT  = (bf16_t*)(ws + o_wvT);
  bf16_t* wov  = (bf16_t*)(ws + o_wov);
  float*  rs   = (float*)(ws + o_rs);
  bf16_t* xT   = (bf16_t*)(ws + o_xT);
  bf16_t* P    = (bf16_t*)(ws + o_xT);  // xT dead once U computed

  const size_t pbytes = 33554432ull;
  const size_t avail = ws_size > o_xT ? ws_size - o_xT : 0;
  int chunk = 1;
  if (avail >= 8 * pbytes) chunk = 8;
  else if (avail >= 4 * pbytes) chunk = 4;
  else if (avail >= 2 * pbytes) chunk = 2;

  const float scale = 0.04419417382415922f;  // 512^-0.5

  cast_f32_bf16<<<2048, 256, 0, stream>>>(wqkv, wqkb, 524288);                // W_q|W_k
  cast_f32_bf16<<<1024, 256, 0, stream>>>(wout, wob, 262144);                 // W_o
  transpose_cast_512<<<dim3(16, 16), 256, 0, stream>>>(wqkv + 524288, wvT);   // W_v^T
  zero_f32<<<128, 256, 0, stream>>>(rs, 32768);
  transpose_cast<<<dim3(128, 16, 8), 256, 0, stream>>>(x, xT);

  // qk proj: A=xT [4096,512], Bt=wqk [1024,512] -> qkT [b][4096][1024]
  gemm8<0><<<dim3(16, 4, 8), 512, 0, stream>>>(
      xT, 2097152LL, 512, wqkb, 0LL, 512, qkT, 4194304LL, 1024, 512, 1.f, nullptr, 0);

  // W_ov = W_o @ W_v: A=W_o [512,512], Bt=W_v^T [512,512]
  gemm8<0><<<dim3(2, 2, 1), 512, 0, stream>>>(
      wob, 0LL, 512, wvT, 0LL, 512, wov, 0LL, 512, 512, 1.f, nullptr, 0);

  // U = W_ov @ x: A=W_ov [512,512], Bt=xT [4096,512] -> U [b][512][4096]
  gemm8<0><<<dim3(2, 16, 8), 512, 0, stream>>>(
      wov, 0LL, 512, xT, 2097152LL, 512, U, 2097152LL, 4096, 512, 1.f, nullptr, 0);

  // attention, chunked over batches (P overlays xT region)
  for (int cb = 0; cb < 8; cb += chunk) {
    // P = exp(scale * q^T k)
    gemm8<2><<<dim3(16, 16, chunk), 512, 0, stream>>>(
        qkT + (size_t)cb * 4194304, 4194304LL, 1024,
        qkT + (size_t)cb * 4194304 + 512, 4194304LL, 1024,
        P, 16777216LL, 4096, 512, scale, rs + cb * 4096, 4096);
    // y = (U @ P^T)/l -> fp32 d_out [b][512][4096]
    gemm8<5><<<dim3(2, 16, chunk), 512, 0, stream>>>(
        U + (size_t)cb * 2097152, 2097152LL, 4096,
        P, 16777216LL, 4096,
        (float*)d_out + (size_t)cb * 2097152, 2097152LL, 4096,
        4096, 1.f, rs + cb * 4096, 4096);
  }
}

// Round 8
// 621.459 us; speedup vs baseline: 1.0249x; 1.0249x over previous
//
#include <hip/hip_runtime.h>
#include <hip/hip_bf16.h>

// ---------------------------------------------------------------------------
// Attention_15573551415521: b=8, c=512, n=4096
//   qk = W_qk x -> qkT[b][n][1024]; W_ov = W_o W_v; U = W_ov x -> [b][512][n]
//   P = exp(scale q^T k); y = (U P^T)/rowsum -> fp32 d_out (split-K atomics)
// 256x256 tile, 8 waves (2Mx4N), BK=64, 2 K-tiles/iter, deep-pipelined 8-phase:
// quarter-tile staging (2 glds16/phase), every unit issued ~3.7 phases before
// its vmcnt(6) gate (T3+T4 at m201 depth), frags read once per K-tile,
// 1 barrier/phase, XOR-swizzled LDS (0 conflicts measured), setprio (T5).
// ---------------------------------------------------------------------------

typedef __bf16 bf16x8 __attribute__((ext_vector_type(8)));
typedef float f32x4 __attribute__((ext_vector_type(4)));
typedef __hip_bfloat16 bf16_t;

static __device__ __forceinline__ void glds16(const void* g, void* l) {
  __builtin_amdgcn_global_load_lds(
      (__attribute__((address_space(1))) const void*)g,
      (__attribute__((address_space(3))) void*)l, 16, 0, 0);
}

#define BAR asm volatile("s_barrier" ::: "memory")
#define LGKM0 asm volatile("s_waitcnt lgkmcnt(0)" ::: "memory")
#define VM0 asm volatile("s_waitcnt vmcnt(0)" ::: "memory")
#define VM6 asm volatile("s_waitcnt vmcnt(6)" ::: "memory")

#define RD_A(buf, fb)                                                       \
  _Pragma("unroll") for (int j = 0; j < 4; ++j)                             \
    _Pragma("unroll") for (int kk = 0; kk < 2; ++kk)                        \
      avr[j][kk] = *(const bf16x8*)(lds + (buf)*32768 +                     \
          ((wm*128 + ((fb)+j)*16 + lr) << 7) + ((kk*64 + lk*16) ^ swz));

#define RD_B(dst, buf, fb)                                                  \
  _Pragma("unroll") for (int n = 0; n < 2; ++n)                             \
    _Pragma("unroll") for (int kk = 0; kk < 2; ++kk)                        \
      dst[n][kk] = *(const bf16x8*)(lds + 65536 + (buf)*32768 +             \
          ((wn*64 + ((fb)+n)*16 + lr) << 7) + ((kk*64 + lk*16) ^ swz));

#define MFMA16(bvx, fb, nb)                                                 \
  __builtin_amdgcn_s_setprio(1);                                            \
  _Pragma("unroll") for (int j = 0; j < 4; ++j)                             \
    _Pragma("unroll") for (int n = 0; n < 2; ++n)                           \
      _Pragma("unroll") for (int kk = 0; kk < 2; ++kk)                      \
        acc[(fb)+j][(nb)+n] = __builtin_amdgcn_mfma_f32_16x16x32_bf16(      \
            avr[j][kk], bvx[n][kk], acc[(fb)+j][(nb)+n], 0, 0, 0);          \
  __builtin_amdgcn_s_setprio(0);

// MODE 0: bf16 store | MODE 2: P=exp(acc*scale) + rowsum atomic (row=M)
// MODE 5: fp32 atomicAdd of acc/rowsum[col] (col=N), split-K via z-parity
template <int MODE, int KSPLIT>
__global__ void __launch_bounds__(512, 2)
gemm8(const bf16_t* __restrict__ A, long long strideA, int lda,
      const bf16_t* __restrict__ Bt, long long strideB, int ldb,
      void* __restrict__ Cv, long long strideC, int ldc,
      int K, float scale, float* __restrict__ rowsum, int strideRS) {
  __shared__ char lds[131072];  // A: buf0 @0, buf1 @32K; B: @64K, @96K
  const int tid = threadIdx.x;
  const int lane = tid & 63;
  const int wid = tid >> 6;
  const int wm = wid >> 2, wn = wid & 3;    // 2 x 4; per-wave out 128x64
  const int lr = lane & 15, lk = lane >> 4;
  const int swz = (lr & 7) << 4;
  const int rowl = tid >> 3;                       // 0..63 within a 64-row unit
  const int kbl = ((tid * 16) & 127) ^ ((rowl & 7) << 4);

  int b = blockIdx.z, ks = 0;
  if (KSPLIT) { ks = b & 1; b >>= 1; }
  const bf16_t* Ap = A + (size_t)ks * K;
  const bf16_t* Btp = Bt + (size_t)ks * K;

  const char* Ab = (const char*)(Ap + (long long)b*strideA + (size_t)blockIdx.x*256*lda);
  const char* Bb = (const char*)(Btp + (long long)b*strideB + (size_t)blockIdx.y*256*ldb);
  const size_t ldab = (size_t)lda*2, ldbb = (size_t)ldb*2;

  // stage quarter-unit u (64 rows, 8KB) of operand m into buf at K-tile kt
  auto stage = [&](int m, int buf, int u, int kt) {
    const char* src = (m ? Bb : Ab) + (size_t)(u*64 + rowl) * (m ? ldbb : ldab)
                      + (size_t)kt*128 + kbl;
    glds16(src, lds + m*65536 + buf*32768 + u*8192 + wid*1024);
  };

  f32x4 acc[8][4] = {};
  bf16x8 avr[4][2], bva[2][2], bvb[2][2];
  const int niter = K >> 7;  // 2 K-tiles/iter, niter >= 2 for all our shapes

  // prologue: tile0 complete (8 units) + tile1's 6 early units; VM6 drains t0
  stage(0,0,0,0); stage(0,0,1,0); stage(0,0,2,0); stage(0,0,3,0);
  stage(1,0,0,0); stage(1,0,1,0); stage(1,0,2,0); stage(1,0,3,0);
  stage(0,1,0,1); stage(0,1,2,1);
  stage(1,1,0,1); stage(1,1,1,1); stage(1,1,2,1); stage(1,1,3,1);
  VM6; BAR;

  for (int i = 0; i < niter; ++i) {
    const bool nl = (i + 1 < niter);
    const int ko = 2*i + 1, ke2 = 2*i + 2, ko3 = 2*i + 3;
    // P0: stage o.A-q1,q3 (freed prev P6); read buf0 av0-3+bv0-1; MFMA(0-3,0-1)
    stage(0,1,1,ko); stage(0,1,3,ko);
    RD_A(0,0); RD_B(bva,0,0);
    MFMA16(bva, 0, 0); LGKM0; BAR;
    // P1: stage e2.A-q0,q2 (freed P0); read bv2-3; MFMA(0-3,2-3)
    if (nl) { stage(0,0,0,ke2); stage(0,0,2,ke2); }
    RD_B(bvb,0,2);
    MFMA16(bvb, 0, 2); LGKM0; BAR;
    // P2: stage e2.B-s0,s1 (freed P1); read av4-7; MFMA(4-7,2-3)
    if (nl) { stage(1,0,0,ke2); stage(1,0,1,ke2); }
    RD_A(0,4);
    MFMA16(bvb, 4, 2); LGKM0; BAR;
    // P3: stage e2.B-s2,s3; MFMA(4-7,0-1) pure-reg; GATE: tile-o fully landed
    if (nl) { stage(1,0,2,ke2); stage(1,0,3,ke2); }
    MFMA16(bva, 4, 0);
    if (nl) { VM6; } else { VM0; }
    BAR;
    // P4: stage e2.A-q1,q3 (freed P2); read buf1 av0-3+bv0-1; MFMA(0-3,0-1)
    if (nl) { stage(0,0,1,ke2); stage(0,0,3,ke2); }
    RD_A(1,0); RD_B(bva,1,0);
    MFMA16(bva, 0, 0); LGKM0; BAR;
    // P5: stage o3.A-q0,q2 (freed P4); read bv2-3; MFMA(0-3,2-3)
    if (nl) { stage(0,1,0,ko3); stage(0,1,2,ko3); }
    RD_B(bvb,1,2);
    MFMA16(bvb, 0, 2); LGKM0; BAR;
    // P6: stage o3.B-s0,s1 (freed P5); read av4-7; MFMA(4-7,2-3)
    if (nl) { stage(1,1,0,ko3); stage(1,1,1,ko3); }
    RD_A(1,4);
    MFMA16(bvb, 4, 2); LGKM0; BAR;
    // P7: stage o3.B-s2,s3; MFMA(4-7,0-1); GATE: tile-e2 fully landed
    if (nl) { stage(1,1,2,ko3); stage(1,1,3,ko3); }
    MFMA16(bva, 4, 0);
    if (nl) { VM6; }
    BAR;
  }

  // epilogue: C/D layout col=lane&15, row=(lane>>4)*4+reg (m89-verified)
  const int mbase = blockIdx.x*256 + wm*128;
  const int nbase = blockIdx.y*256 + wn*64;

  if (MODE == 0) {
    bf16_t* C = (bf16_t*)Cv + (long long)b * strideC;
#pragma unroll
    for (int fm = 0; fm < 8; ++fm)
#pragma unroll
      for (int fn = 0; fn < 4; ++fn)
#pragma unroll
        for (int r = 0; r < 4; ++r) {
          const int row = mbase + fm*16 + lk*4 + r;
          const int col = nbase + fn*16 + lr;
          C[(size_t)row*ldc + col] = __float2bfloat16(acc[fm][fn][r]);
        }
  } else if (MODE == 2) {
    bf16_t* P = (bf16_t*)Cv + (long long)b * strideC;
    float* rs = rowsum + (long long)b * strideRS;
#pragma unroll
    for (int fm = 0; fm < 8; ++fm)
#pragma unroll
      for (int r = 0; r < 4; ++r) {
        const int row = mbase + fm*16 + lk*4 + r;
        float s = 0.f;
#pragma unroll
        for (int fn = 0; fn < 4; ++fn) {
          const float v = __expf(acc[fm][fn][r] * scale);
          const int col = nbase + fn*16 + lr;
          P[(size_t)row*ldc + col] = __float2bfloat16(v);
          s += v;
        }
        s += __shfl_xor(s, 1);
        s += __shfl_xor(s, 2);
        s += __shfl_xor(s, 4);
        s += __shfl_xor(s, 8);
        if (lr == 0) atomicAdd(&rs[row], s);
      }
  } else {  // MODE 5: atomicAdd partial (split-K), normalized by rowsum[col]
    float* O = (float*)Cv + (long long)b * strideC;
    const float* rs = rowsum + (long long)b * strideRS;
#pragma unroll
    for (int fn = 0; fn < 4; ++fn) {
      const int col = nbase + fn*16 + lr;
      const float inv = 1.0f / rs[col];
#pragma unroll
      for (int fm = 0; fm < 8; ++fm)
#pragma unroll
        for (int r = 0; r < 4; ++r) {
          const int row = mbase + fm*16 + lk*4 + r;
          atomicAdd(&O[(size_t)row*ldc + col], acc[fm][fn][r] * inv);
        }
    }
  }
}

__global__ void cast_f32_bf16(const float* __restrict__ in, bf16_t* __restrict__ out, int n) {
  const int i = blockIdx.x * blockDim.x + threadIdx.x;
  if (i < n) out[i] = __float2bfloat16(in[i]);
}

__global__ void zero_f32(float* __restrict__ p, int n) {
  for (int i = blockIdx.x * blockDim.x + threadIdx.x; i < n; i += gridDim.x * blockDim.x)
    p[i] = 0.f;
}

// x [8][512][4096] f32 -> xT [8][4096][512] bf16
__global__ void transpose_cast(const float* __restrict__ x, bf16_t* __restrict__ xT) {
  __shared__ float t[32][33];
  const int b = blockIdx.z;
  const int n0 = blockIdx.x * 32, c0 = blockIdx.y * 32;
  const int tx = threadIdx.x & 31, ty = threadIdx.x >> 5;  // 32x8
  const float* xb = x + (size_t)b * (512 * 4096);
#pragma unroll
  for (int i = 0; i < 32; i += 8)
    t[ty + i][tx] = xb[(size_t)(c0 + ty + i) * 4096 + n0 + tx];
  __syncthreads();
  bf16_t* xo = xT + (size_t)b * (4096 * 512);
#pragma unroll
  for (int i = 0; i < 32; i += 8)
    xo[(size_t)(n0 + ty + i) * 512 + c0 + tx] = __float2bfloat16(t[tx][ty + i]);
}

// 512x512 f32 -> transposed bf16 (for W_v^T)
__global__ void transpose_cast_512(const float* __restrict__ in, bf16_t* __restrict__ out) {
  __shared__ float t[32][33];
  const int r0 = blockIdx.x * 32, c0 = blockIdx.y * 32;
  const int tx = threadIdx.x & 31, ty = threadIdx.x >> 5;
#pragma unroll
  for (int i = 0; i < 32; i += 8)
    t[ty + i][tx] = in[(size_t)(r0 + ty + i) * 512 + c0 + tx];
  __syncthreads();
#pragma unroll
  for (int i = 0; i < 32; i += 8)
    out[(size_t)(c0 + ty + i) * 512 + r0 + tx] = __float2bfloat16(t[tx][ty + i]);
}

extern "C" void kernel_launch(void* const* d_in, const int* in_sizes, int n_in,
                              void* d_out, int out_size, void* d_ws, size_t ws_size,
                              hipStream_t stream) {
  const float* x = (const float*)d_in[0];
  const float* wqkv = (const float*)d_in[1];
  const float* wout = (const float*)d_in[2];
  char* ws = (char*)d_ws;

  const size_t o_qkT = 0;             // 8*4096*1024*2 = 67108864
  const size_t o_U   = 67108864ull;   // 8*512*4096*2  = 33554432
  const size_t o_wqk = 100663296ull;  // 1048576
  const size_t o_wo  = 101711872ull;  // 524288
  const size_t o_wvT = 102236160ull;  // 524288
  const size_t o_wov = 102760448ull;  // 524288
  const size_t o_rs  = 103284736ull;  // 131072
  const size_t o_xT  = 103415808ull;  // 33554432; P overlays xT afterwards

  bf16_t* qkT  = (bf16_t*)(ws + o_qkT);
  bf16_t* U    = (bf16_t*)(ws + o_U);
  bf16_t* wqkb = (bf16_t*)(ws + o_wqk);
  bf16_t* wob  = (bf16_t*)(ws + o_wo);
  bf16_t* wvT  = (bf16_t*)(ws + o_wvT);
  bf16_t* wov  = (bf16_t*)(ws + o_wov);
  float*  rs   = (float*)(ws + o_rs);
  bf16_t* xT   = (bf16_t*)(ws + o_xT);
  bf16_t* P    = (bf16_t*)(ws + o_xT);  // xT dead once U computed

  const size_t pbytes = 33554432ull;
  const size_t avail = ws_size > o_xT ? ws_size - o_xT : 0;
  int chunk = 1;
  if (avail >= 8 * pbytes) chunk = 8;
  else if (avail >= 4 * pbytes) chunk = 4;
  else if (avail >= 2 * pbytes) chunk = 2;

  const float scale = 0.04419417382415922f;  // 512^-0.5

  cast_f32_bf16<<<2048, 256, 0, stream>>>(wqkv, wqkb, 524288);                // W_q|W_k
  cast_f32_bf16<<<1024, 256, 0, stream>>>(wout, wob, 262144);                 // W_o
  transpose_cast_512<<<dim3(16, 16), 256, 0, stream>>>(wqkv + 524288, wvT);   // W_v^T
  zero_f32<<<128, 256, 0, stream>>>(rs, 32768);
  zero_f32<<<2048, 256, 0, stream>>>((float*)d_out, out_size);                // for split-K atomics
  transpose_cast<<<dim3(128, 16, 8), 256, 0, stream>>>(x, xT);

  // qk proj: A=xT [4096,512], Bt=wqk [1024,512] -> qkT [b][4096][1024]
  gemm8<0,0><<<dim3(16, 4, 8), 512, 0, stream>>>(
      xT, 2097152LL, 512, wqkb, 0LL, 512, qkT, 4194304LL, 1024, 512, 1.f, nullptr, 0);

  // W_ov = W_o @ W_v
  gemm8<0,0><<<dim3(2, 2, 1), 512, 0, stream>>>(
      wob, 0LL, 512, wvT, 0LL, 512, wov, 0LL, 512, 512, 1.f, nullptr, 0);

  // U = W_ov @ x: A=W_ov [512,512], Bt=xT [4096,512] -> U [b][512][4096]
  gemm8<0,0><<<dim3(2, 16, 8), 512, 0, stream>>>(
      wov, 0LL, 512, xT, 2097152LL, 512, U, 2097152LL, 4096, 512, 1.f, nullptr, 0);

  // attention, chunked over batches (P overlays xT region)
  for (int cb = 0; cb < 8; cb += chunk) {
    // P = exp(scale * q^T k)
    gemm8<2,0><<<dim3(16, 16, chunk), 512, 0, stream>>>(
        qkT + (size_t)cb * 4194304, 4194304LL, 1024,
        qkT + (size_t)cb * 4194304 + 512, 4194304LL, 1024,
        P, 16777216LL, 4096, 512, scale, rs + cb * 4096, 4096);
    // y += (U @ P^T)/l, split-K=2 (full-machine grid), fp32 atomics
    gemm8<5,1><<<dim3(2, 16, chunk * 2), 512, 0, stream>>>(
        U + (size_t)cb * 2097152, 2097152LL, 4096,
        P, 16777216LL, 4096,
        (float*)d_out + (size_t)cb * 2097152, 2097152LL, 4096,
        2048, 1.f, rs + cb * 4096, 4096);
  }
}